// Round 13
// baseline (1990.040 us; speedup 1.0000x reference)
//
#include <hip/hip_runtime.h>

// Problem: VQ-VAE codebook. z [32,256,32,32] f32, emb [8192,256] f32.
// Outputs concatenated in d_out (f32): z_q [8388608], idx [32768] (as float), loss [1].
//
// Scratch layout inside d_out's z_q region (consumed before k_out overwrites it):
//   [0 .. 2097152)        embT  (256 x 8192)   transposed codebook
//   [2097152 .. 2105344)  se    (8192)         ||e_k||^2
//   [2105344 .. 2138112)  sz    (32768)        ||z_n||^2
#define ZQ_OFF   0
#define EMBT_OFF 0
#define SE_OFF   2097152
#define SZ_OFF   2105344
#define IDX_OFF  8388608
#define LOSS_OFF 8421376

typedef float f32x2 __attribute__((ext_vector_type(2)));

// ---- fused prep: coalesced 64x64 LDS transpose emb -> embT[d][k]  +  se[k]  +  sz[n]
// blocks 0..511: transpose; 512..2559: se; 2560..2687: sz
__global__ void k_prep(const float* __restrict__ emb, float* __restrict__ embT,
                       float* __restrict__ se, const float* __restrict__ z,
                       float* __restrict__ sz) {
    const int blk = blockIdx.x;
    if (blk < 512) {
        __shared__ float tile[64][65];
        const int k0 = (blk & 127) * 64;          // 8192/64 = 128
        const int d0 = (blk >> 7) * 64;           // 256/64 = 4
        const int lane = threadIdx.x & 63;
        const int grp  = threadIdx.x >> 6;        // 0..3
        // read: 64 rows of emb (k), 64 cols (d) — coalesced along d
        #pragma unroll
        for (int i = 0; i < 16; ++i) {
            const int r = grp * 16 + i;
            tile[r][lane] = emb[(size_t)(k0 + r) * 256 + d0 + lane];
        }
        __syncthreads();
        // write: embT[d][k] — coalesced along k; tile read transposed (pad 65 -> conflict-free)
        #pragma unroll
        for (int i = 0; i < 16; ++i) {
            const int r = grp * 16 + i;
            embT[(size_t)(d0 + r) * 8192 + k0 + lane] = tile[lane][r];
        }
    } else if (blk < 2560) {
        int w    = ((blk - 512) * 256 + threadIdx.x) >> 6;    // code id
        int lane = threadIdx.x & 63;
        float4 v = *(const float4*)(emb + (size_t)w * 256 + lane * 4);
        float s = v.x * v.x + v.y * v.y + v.z * v.z + v.w * v.w;
        #pragma unroll
        for (int off = 1; off < 64; off <<= 1) s += __shfl_xor(s, off);
        if (lane == 0) se[w] = s;
    } else {
        // sz[n] = sum over c of z[b][c][hw]^2 (sequential chain over c ascending)
        int n  = (blk - 2560) * 256 + threadIdx.x;   // 128 blocks
        int b  = n >> 10, hw = n & 1023;
        const float* zp = z + (size_t)b * 262144 + hw;
        float acc = 0.f;
        #pragma unroll 8
        for (int c = 0; c < 256; ++c) { float v = zp[(size_t)c << 10]; acc += v * v; }
        sz[n] = acc;
    }
}

// packed dual FMA on a row-pair (z pair) x one code; EP holds 2 codes, op_sel picks which.
// even code: D.lo = z.lo*e.lo+acc.lo ; D.hi = z.hi*e.lo+acc.hi
#define PKFMA_EVEN(ACC, ZP, EP) \
    asm("v_pk_fma_f32 %0, %1, %2, %0 op_sel:[0,0,0] op_sel_hi:[1,0,1]" \
        : "+v"(ACC) : "v"(ZP), "v"(EP))
// odd code:  D.lo = z.lo*e.hi+acc.lo ; D.hi = z.hi*e.hi+acc.hi
#define PKFMA_ODD(ACC, ZP, EP) \
    asm("v_pk_fma_f32 %0, %1, %2, %0 op_sel:[0,1,0] op_sel_hi:[1,1,1]" \
        : "+v"(ACC) : "v"(ZP), "v"(EP))

// one d: 16 rows (8 z-pairs) x 8 codes (4 ef-pairs) = 64 pk ops = 128 FMAs.
// Each component is an IEEE fma -> bit-identical to the scalar fmaf chain.
#define FMA_BLOCK(Z, E0, E1) do {                                        \
    f32x2 ep_[4];                                                         \
    ep_[0] = ((const f32x2*)&(E0))[0]; ep_[1] = ((const f32x2*)&(E0))[1]; \
    ep_[2] = ((const f32x2*)&(E1))[0]; ep_[3] = ((const f32x2*)&(E1))[1]; \
    _Pragma("unroll")                                                     \
    for (int p_ = 0; p_ < 8; ++p_) {                                      \
        const f32x2 zp_ = ((const f32x2*)&(Z)[p_ >> 1])[p_ & 1];          \
        _Pragma("unroll")                                                 \
        for (int cp_ = 0; cp_ < 4; ++cp_) {                               \
            PKFMA_EVEN(accp[p_][cp_ * 2],     zp_, ep_[cp_]);             \
            PKFMA_ODD (accp[p_][cp_ * 2 + 1], zp_, ep_[cp_]);             \
        }                                                                 \
    }                                                                     \
} while (0)

#define LOADZ(DST, DD) do {                                              \
    _Pragma("unroll")                                                     \
    for (int i_ = 0; i_ < 4; ++i_)                                        \
        (DST)[i_] = *(const float4*)&ztT[DD][i_ * 4];                     \
} while (0)

#define LOADE(EA, EB, PTR, DD) do {                                      \
    const float* p_ = (PTR) + (size_t)(DD) * 8192;                        \
    (EA) = *(const float4*)(p_);                                          \
    (EB) = *(const float4*)(p_ + 4);                                      \
} while (0)

// ---- main: exact-f32-replica distance + argmin.
// Structure = R12 (3-slot rotation pipeline, v_pk_fma_f32, 4-way code split, 16 rows/blk,
// grid 2048) + cross-tile load overlap: next tile's ef/z slot loads are issued BEFORE the
// current tile's epilogue, so the ~600-instr argmin epilogue hides the pipeline refill.
// Per-tile argmin folded into LDS cwd/cwk (full lowest-k tie-break).
// d_nk = fl( fl(sz_n + se_k) - 2*m_nk ),  m = sequential fmaf chain over d=0..255 (BLAS order)
__global__ __launch_bounds__(256, 2) void k_main(
    const float* __restrict__ z, const float* __restrict__ embT,
    const float* __restrict__ se, const float* __restrict__ sz,
    float* __restrict__ idxf, float* __restrict__ lossslot) {
    __shared__ float ztT[256][16];        // [d][row]
    __shared__ float szs[16];
    __shared__ float cwd[4][16];          // [codegrp][row] best distance
    __shared__ int   cwk[4][16];          // matching code id
    const int tid = threadIdx.x;
    const int blk = blockIdx.x;           // grid = 2048
    const int n0  = blk * 16;
    const int b   = n0 >> 10, hw0 = n0 & 1023;

    // stage z tile transposed: ztT[c][n]; coalesced global reads over n
    {
        const int n  = tid & 15;
        const int cg = tid >> 4;                        // 0..15
        const float* zp = z + (size_t)b * 262144 + hw0 + n;
        #pragma unroll
        for (int cc = 0; cc < 256; cc += 16)
            ztT[cc + cg][n] = zp[(size_t)(cc + cg) << 10];
        if (tid < 16) szs[tid] = sz[n0 + tid];
        if (tid < 64) { (&cwd[0][0])[tid] = 3.4e38f; (&cwk[0][0])[tid] = 0; }
    }
    __syncthreads();

    const int w = tid >> 6;       // wave 0..3 -> code quarter w*512 within each tile
    const int j = tid & 63;       // lane -> 8 codes
    const int cbase = w * 512 + j * 8;

    // pipeline slots live across tiles
    float4 z0[4], z1[4], z2[4];
    float4 e0a, e0b, e1a, e1b, e2a, e2b;
    {
        const float* ep0 = embT + cbase;
        LOADZ(z0, 0);
        LOADE(e0a, e0b, ep0, 0);
        LOADE(e1a, e1b, ep0, 1);
        LOADE(e2a, e2b, ep0, 2);
    }

    for (int tile = 0; tile < 4; ++tile) {
        const int c0 = tile * 2048 + cbase;
        const float* ep = embT + c0;

        f32x2 accp[8][8];
        #pragma unroll
        for (int p = 0; p < 8; ++p)
            #pragma unroll
            for (int c = 0; c < 8; ++c) { accp[p][c].x = 0.f; accp[p][c].y = 0.f; }

        // invariant entering body at `base`: z0 holds d=base, e_i holds d=base+i
        #pragma unroll 1
        for (int base = 0; base < 255; base += 3) {
            // pos 0: d = base
            LOADZ(z1, base + 1);
            FMA_BLOCK(z0, e0a, e0b);
            LOADE(e0a, e0b, ep, base + 3);
            // pos 1: d = base+1
            LOADZ(z2, base + 2);
            FMA_BLOCK(z1, e1a, e1b);
            LOADE(e1a, e1b, ep, base + 4);
            // pos 2: d = base+2
            LOADZ(z0, base + 3);
            FMA_BLOCK(z2, e2a, e2b);
            LOADE(e2a, e2b, ep, base + 5);
        }
        // tail: d = 255 (z0/e0 were set in the last body). Overshoot ef reads (rows
        // 256,257) land in the se/sz scratch region (valid memory, never consumed).
        FMA_BLOCK(z0, e0a, e0b);

        // issue NEXT tile's slot loads now; the epilogue below hides their latency
        if (tile < 3) {
            const float* epn = embT + (tile + 1) * 2048 + cbase;
            LOADE(e0a, e0b, epn, 0);
            LOADE(e1a, e1b, epn, 1);
            LOADE(e2a, e2b, epn, 2);
            LOADZ(z0, 0);
        }

        // epilogue: dq = fl( fl(sz+se) - 2m ); codes ascending; strict < keeps first min
        const float4 seA = *(const float4*)(se + c0);
        const float4 seB = *(const float4*)(se + c0 + 4);
        #pragma unroll
        for (int rr = 0; rr < 16; ++rr) {
            const float szv = szs[rr];
            float bd = 3.4e38f; int bk = 0;
            #pragma unroll
            for (int c = 0; c < 8; ++c) {
                const float sek = (c < 4) ? ((const float*)&seA)[c]
                                          : ((const float*)&seB)[c - 4];
                const float m  = (rr & 1) ? accp[rr >> 1][c].y : accp[rr >> 1][c].x;
                float A  = szv + sek;
                float dq = A - 2.0f * m;
                if (dq < bd) { bd = dq; bk = c0 + c; }
            }
            // butterfly across 64 lanes; tie-break lowest k
            #pragma unroll
            for (int off = 1; off < 64; off <<= 1) {
                float od = __shfl_xor(bd, off);
                int   ok = __shfl_xor(bk, off);
                if (od < bd || (od == bd && ok < bk)) { bd = od; bk = ok; }
            }
            if (j == 0) {
                float pd = cwd[w][rr]; int pk = cwk[w][rr];
                if (bd < pd || (bd == pd && bk < pk)) { cwd[w][rr] = bd; cwk[w][rr] = bk; }
            }
        }
    }
    __syncthreads();
    // merge the 4 code-group partials per row with full (d,k) tie-break
    if (tid < 16) {
        float d = cwd[0][tid]; int k = cwk[0][tid];
        #pragma unroll
        for (int ww = 1; ww < 4; ++ww) {
            float od = cwd[ww][tid]; int ok = cwk[ww][tid];
            if (od < d || (od == d && ok < k)) { d = od; k = ok; }
        }
        idxf[n0 + tid] = (float)k;
    }
    if (blk == 0 && tid == 0) *lossslot = 0.f;   // init loss accumulator (runs before k_out)
}

// ---- z_q (STE-exact) + loss partial sums
__global__ void k_out(const float* __restrict__ z, const float* __restrict__ emb,
                      const float* __restrict__ idxf, float* __restrict__ zq,
                      float* __restrict__ lossslot) {
    int u   = blockIdx.x * 256 + threadIdx.x;   // grid = 8192 blocks (2M threads)
    int cc4 = u >> 15;                          // 0..63 (uniform per block)
    int n   = u & 32767;
    int b   = n >> 10, hw = n & 1023;
    int k   = (int)idxf[n];
    const float4 q4 = *(const float4*)(emb + (size_t)k * 256 + cc4 * 4);
    float ls = 0.f;
    #pragma unroll
    for (int c = 0; c < 4; ++c) {
        size_t zi = (size_t)b * 262144 + (size_t)(cc4 * 4 + c) * 1024 + hw;
        float zv   = z[zi];
        float qv   = ((const float*)&q4)[c];
        float diff = qv - zv;        // fl(q - z)
        zq[zi]     = zv + diff;      // fl(z + fl(q - z))  == reference STE output
        ls += diff * diff;
    }
    #pragma unroll
    for (int off = 1; off < 64; off <<= 1) ls += __shfl_xor(ls, off);
    if ((threadIdx.x & 63) == 0) atomicAdd(lossslot, ls);
}

__global__ void k_fin(float* __restrict__ lossslot) {
    float S = *lossslot;
    float m = S / 8388608.0f;        // /2^23 exact scaling
    *lossslot = m + 0.25f * m;       // fl(m1 + fl(beta*m2)), m1==m2
}

extern "C" void kernel_launch(void* const* d_in, const int* in_sizes, int n_in,
                              void* d_out, int out_size, void* d_ws, size_t ws_size,
                              hipStream_t stream) {
    const float* z   = (const float*)d_in[0];
    const float* emb = (const float*)d_in[1];
    float* out  = (float*)d_out;
    float* embT = out + EMBT_OFF;
    float* se   = out + SE_OFF;
    float* sz   = out + SZ_OFF;
    float* idxf = out + IDX_OFF;
    float* loss = out + LOSS_OFF;

    k_prep<<<2688, 256, 0, stream>>>(emb, embT, se, z, sz);
    k_main<<<2048, 256, 0, stream>>>(z, embT, se, sz, idxf, loss);
    k_out<<<8192, 256, 0, stream>>>(z, emb, idxf, out + ZQ_OFF, loss);
    k_fin<<<1, 1, 0, stream>>>(loss);
}